// Round 6
// baseline (170.296 us; speedup 1.0000x reference)
//
#include <hip/hip_runtime.h>

// Problem constants: B=8, T=12 (BT=96), N=10000, D=16, E=160000
#define NN  10000
#define NE  160000
#define NBT 96
#define DD  16

#define SCAN_THREADS 1024
#define SCHUNK 10                 // ceil(NN / SCAN_THREADS)

#define NODES_PER_BLOCK 64
#define NCHUNK 157                // ceil(NN / NODES_PER_BLOCK)
#define NXCD 8
#define BTD_MAX 6                 // thread handles bt and bt+48

#define NBUCKET 64
#define NEP (NE + 3 * NN)         // padded edge capacity (pad-to-4 worst case)

// ---------------- CSR build ----------------

__global__ void k_hist(const int* __restrict__ dst, int* __restrict__ counts) {
    int e = blockIdx.x * blockDim.x + threadIdx.x;
    if (e < NE) atomicAdd(&counts[dst[e]], 1);
}

// Single-block: exclusive scan of padded degrees -> offsets/cursor, plus
// degree-bucket histogram -> exclusive bucket bases in bcur.
__global__ __launch_bounds__(SCAN_THREADS) void k_scan(const int* __restrict__ counts,
                                                       int* __restrict__ offsets,
                                                       int* __restrict__ cursor,
                                                       int* __restrict__ bcur) {
    __shared__ int part[SCAN_THREADS];
    __shared__ int bh[NBUCKET];
    int tid = threadIdx.x;
    if (tid < NBUCKET) bh[tid] = 0;
    __syncthreads();

    int begin = tid * SCHUNK;
    int end   = min(begin + SCHUNK, NN);
    int s = 0;
    for (int i = begin; i < end; ++i) {
        int d = counts[i];
        s += (d + 3) & ~3;
        atomicAdd(&bh[min(d, NBUCKET - 1)], 1);
    }
    part[tid] = s;
    __syncthreads();
    for (int off = 1; off < SCAN_THREADS; off <<= 1) {
        int v = (tid >= off) ? part[tid - off] : 0;
        __syncthreads();
        part[tid] += v;
        __syncthreads();
    }
    int run = (tid == 0) ? 0 : part[tid - 1];
    for (int i = begin; i < end; ++i) {
        int d = counts[i];
        offsets[i] = run;
        cursor[i]  = run;
        run += (d + 3) & ~3;
    }
    if (tid == SCAN_THREADS - 1) offsets[NN] = part[SCAN_THREADS - 1];

    __syncthreads();
    if (tid == 0) {
        int acc = 0;
        for (int b = 0; b < NBUCKET; ++b) { int c = bh[b]; bcur[b] = acc; acc += c; }
    }
}

// Node-parallel: degree-bucket scatter (perm) + NaN sentinel pad writes.
// fmaxf(acc, NaN*v) == acc under IEEE v_max_f32, so pad slots are no-ops.
__global__ void k_node(const int* __restrict__ counts, const int* __restrict__ offsets,
                       int* __restrict__ bcur, int* __restrict__ perm,
                       int* __restrict__ esrc, float* __restrict__ ew) {
    int n = blockIdx.x * blockDim.x + threadIdx.x;
    if (n >= NN) return;
    int d = counts[n];
    int pos = atomicAdd(&bcur[min(d, NBUCKET - 1)], 1);
    perm[pos] = n;
    int beg  = offsets[n];
    int pdeg = (d + 3) & ~3;
    const float qnan = __int_as_float(0x7FC00000);
    for (int p = beg + d; p < beg + pdeg; ++p) { esrc[p] = 0; ew[p] = qnan; }
}

__global__ void k_scatter(const int* __restrict__ src, const int* __restrict__ dst,
                          const float* __restrict__ w,
                          int* __restrict__ cursor,
                          int* __restrict__ esrc, float* __restrict__ ew) {
    int e = blockIdx.x * blockDim.x + threadIdx.x;
    if (e >= NE) return;
    int d = dst[e];
    int pos = atomicAdd(&cursor[d], 1);
    esrc[pos] = src[e];
    ew[pos]   = w[e];
}

// ---------------- main gather-max ----------------
// One block = (bt pair {bt0, bt0+48}, 64-sorted-node chunk). 256 thr = 64 x 4 d4.
// XCD pinning: idx%8 = XCD -> the 1.28 MB V pair stays L2-resident.
// PERM=true: nodes visited in degree-sorted order (waves have uniform trip
// counts; rows padded to x4 with NaN sentinels, so no tail loop).
template <bool PERM>
__global__ __launch_bounds__(256) void k_main(const float* __restrict__ V,
                                              const int* __restrict__ offsets,
                                              const int* __restrict__ perm,
                                              const int* __restrict__ esrc,
                                              const float* __restrict__ ew,
                                              float* __restrict__ out) {
    int idx = blockIdx.x;
    int r   = idx & 7;
    int k   = idx >> 3;
    int btd = k / NCHUNK;             // 0..5
    int chunk = k - btd * NCHUNK;     // 0..156
    int bt0 = r + 8 * btd;            // 0..47
    int bt1 = bt0 + 48;               // 48..95

    int tid = threadIdx.x;
    int i   = chunk * NODES_PER_BLOCK + (tid >> 2);
    int d4  = (tid & 3) << 2;
    if (i >= NN) return;              // no LDS/sync: early-exit safe
    int n = PERM ? perm[i] : i;

    const float* __restrict__ Va = V + (size_t)bt0 * (NN * DD) + d4;
    const float* __restrict__ Vb = V + (size_t)bt1 * (NN * DD) + d4;

    int beg  = offsets[n];
    int endo = offsets[n + 1];

    const float ninf = -__builtin_huge_valf();
    float4 accA = {ninf, ninf, ninf, ninf};
    float4 accB = {ninf, ninf, ninf, ninf};

    int j = beg;
    for (; j + 4 <= endo; j += 4) {
        int   s0 = esrc[j],   s1 = esrc[j+1], s2 = esrc[j+2], s3 = esrc[j+3];
        float w0 = ew[j],     w1 = ew[j+1],   w2 = ew[j+2],   w3 = ew[j+3];
        float4 a0 = *reinterpret_cast<const float4*>(Va + s0 * DD);
        float4 a1 = *reinterpret_cast<const float4*>(Va + s1 * DD);
        float4 a2 = *reinterpret_cast<const float4*>(Va + s2 * DD);
        float4 a3 = *reinterpret_cast<const float4*>(Va + s3 * DD);
        float4 b0 = *reinterpret_cast<const float4*>(Vb + s0 * DD);
        float4 b1 = *reinterpret_cast<const float4*>(Vb + s1 * DD);
        float4 b2 = *reinterpret_cast<const float4*>(Vb + s2 * DD);
        float4 b3 = *reinterpret_cast<const float4*>(Vb + s3 * DD);
        accA.x = fmaxf(accA.x, fmaxf(fmaxf(a0.x*w0, a1.x*w1), fmaxf(a2.x*w2, a3.x*w3)));
        accA.y = fmaxf(accA.y, fmaxf(fmaxf(a0.y*w0, a1.y*w1), fmaxf(a2.y*w2, a3.y*w3)));
        accA.z = fmaxf(accA.z, fmaxf(fmaxf(a0.z*w0, a1.z*w1), fmaxf(a2.z*w2, a3.z*w3)));
        accA.w = fmaxf(accA.w, fmaxf(fmaxf(a0.w*w0, a1.w*w1), fmaxf(a2.w*w2, a3.w*w3)));
        accB.x = fmaxf(accB.x, fmaxf(fmaxf(b0.x*w0, b1.x*w1), fmaxf(b2.x*w2, b3.x*w3)));
        accB.y = fmaxf(accB.y, fmaxf(fmaxf(b0.y*w0, b1.y*w1), fmaxf(b2.y*w2, b3.y*w3)));
        accB.z = fmaxf(accB.z, fmaxf(fmaxf(b0.z*w0, b1.z*w1), fmaxf(b2.z*w2, b3.z*w3)));
        accB.w = fmaxf(accB.w, fmaxf(fmaxf(b0.w*w0, b1.w*w1), fmaxf(b2.w*w2, b3.w*w3)));
    }
    if (!PERM) {
        for (; j < endo; ++j) {
            int   s  = esrc[j];
            float we = ew[j];
            float4 a = *reinterpret_cast<const float4*>(Va + s * DD);
            float4 b = *reinterpret_cast<const float4*>(Vb + s * DD);
            accA.x = fmaxf(accA.x, a.x * we);
            accA.y = fmaxf(accA.y, a.y * we);
            accA.z = fmaxf(accA.z, a.z * we);
            accA.w = fmaxf(accA.w, a.w * we);
            accB.x = fmaxf(accB.x, b.x * we);
            accB.y = fmaxf(accB.y, b.y * we);
            accB.z = fmaxf(accB.z, b.z * we);
            accB.w = fmaxf(accB.w, b.w * we);
        }
    }

    float4 ra, rb;
    ra.x = (accA.x == ninf) ? 0.0f : accA.x;
    ra.y = (accA.y == ninf) ? 0.0f : accA.y;
    ra.z = (accA.z == ninf) ? 0.0f : accA.z;
    ra.w = (accA.w == ninf) ? 0.0f : accA.w;
    rb.x = (accB.x == ninf) ? 0.0f : accB.x;
    rb.y = (accB.y == ninf) ? 0.0f : accB.y;
    rb.z = (accB.z == ninf) ? 0.0f : accB.z;
    rb.w = (accB.w == ninf) ? 0.0f : accB.w;
    *reinterpret_cast<float4*>(out + ((size_t)bt0 * NN + n) * DD + d4) = ra;
    *reinterpret_cast<float4*>(out + ((size_t)bt1 * NN + n) * DD + d4) = rb;
}

// plain scan for the (unlikely) small-ws fallback
__global__ __launch_bounds__(SCAN_THREADS) void k_scan_plain(const int* __restrict__ counts,
                                                             int* __restrict__ offsets,
                                                             int* __restrict__ cursor) {
    __shared__ int part[SCAN_THREADS];
    int tid = threadIdx.x;
    int begin = tid * SCHUNK;
    int end   = min(begin + SCHUNK, NN);
    int s = 0;
    for (int i = begin; i < end; ++i) s += counts[i];
    part[tid] = s;
    __syncthreads();
    for (int off = 1; off < SCAN_THREADS; off <<= 1) {
        int v = (tid >= off) ? part[tid - off] : 0;
        __syncthreads();
        part[tid] += v;
        __syncthreads();
    }
    int run = (tid == 0) ? 0 : part[tid - 1];
    for (int i = begin; i < end; ++i) {
        offsets[i] = run;
        cursor[i]  = run;
        run += counts[i];
    }
    if (tid == SCAN_THREADS - 1) offsets[NN] = part[SCAN_THREADS - 1];
}

// ---------------- launch ----------------

extern "C" void kernel_launch(void* const* d_in, const int* in_sizes, int n_in,
                              void* d_out, int out_size, void* d_ws, size_t ws_size,
                              hipStream_t stream) {
    const float* V   = (const float*)d_in[0];
    const int*   src = (const int*)d_in[1];
    const int*   dst = (const int*)d_in[2];
    const float* w   = (const float*)d_in[3];
    float* out = (float*)d_out;

    int nblocks = NXCD * BTD_MAX * NCHUNK;   // 7536

    // ws layout (4B elems):
    // counts[NN] | offsets[NN+1] | cursor[NN] | perm[NN] | bcur[NBUCKET] | esrc[cap] | ew[cap]
    size_t need = (size_t)(4 * NN + 1 + NBUCKET + 2 * NEP) * 4;
    int* ws_i = (int*)d_ws;
    int*   counts  = ws_i;
    int*   offsets = ws_i + NN;
    int*   cursor  = ws_i + 2 * NN + 1;
    int*   perm    = ws_i + 3 * NN + 1;
    int*   bcur    = ws_i + 4 * NN + 1;

    if (ws_size >= need) {
        int*   esrc = ws_i + 4 * NN + 1 + NBUCKET;
        float* ew   = (float*)(esrc + NEP);

        hipMemsetAsync(counts, 0, NN * sizeof(int), stream);
        k_hist<<<(NE + 255) / 256, 256, 0, stream>>>(dst, counts);
        k_scan<<<1, SCAN_THREADS, 0, stream>>>(counts, offsets, cursor, bcur);
        k_node<<<(NN + 255) / 256, 256, 0, stream>>>(counts, offsets, bcur, perm, esrc, ew);
        k_scatter<<<(NE + 255) / 256, 256, 0, stream>>>(src, dst, w, cursor, esrc, ew);
        k_main<true><<<nblocks, 256, 0, stream>>>(V, offsets, perm, esrc, ew, out);
    } else {
        // fallback: no perm, no padding
        int*   esrc = ws_i + 3 * NN + 1;
        float* ew   = (float*)(esrc + NE);
        hipMemsetAsync(counts, 0, NN * sizeof(int), stream);
        k_hist<<<(NE + 255) / 256, 256, 0, stream>>>(dst, counts);
        k_scan_plain<<<1, SCAN_THREADS, 0, stream>>>(counts, offsets, cursor);
        k_scatter<<<(NE + 255) / 256, 256, 0, stream>>>(src, dst, w, cursor, esrc, ew);
        k_main<false><<<nblocks, 256, 0, stream>>>(V, offsets, perm, esrc, ew, out);
    }
}

// Round 7
// 132.597 us; speedup vs baseline: 1.2843x; 1.2843x over previous
//
#include <hip/hip_runtime.h>

// Problem constants: B=8, T=12 (BT=96), N=10000, D=16, E=160000
#define NN  10000
#define NE  160000
#define NBT 96
#define DD  16

#define SCAN_THREADS 1024
#define SCHUNK 10                 // ceil(NN / SCAN_THREADS)

#define NODES_PER_BLOCK 64
#define NCHUNK 157                // ceil(NN / NODES_PER_BLOCK)
#define NXCD 8
#define BTD_MAX 6                 // thread handles bt and bt+48

#define NEP 190000                // NE + 3*NN, 16B-aligned element count

// ---------------- CSR build ----------------

__global__ void k_hist(const int* __restrict__ dst, int* __restrict__ counts) {
    int e = blockIdx.x * blockDim.x + threadIdx.x;
    if (e < NE) atomicAdd(&counts[dst[e]], 1);
}

// Single-block exclusive scan of pad-to-4 degrees -> offsets/cursor.
__global__ __launch_bounds__(SCAN_THREADS) void k_scan(const int* __restrict__ counts,
                                                       int* __restrict__ offsets,
                                                       int* __restrict__ cursor,
                                                       int pad) {
    __shared__ int part[SCAN_THREADS];
    int tid = threadIdx.x;
    int begin = tid * SCHUNK;
    int end   = min(begin + SCHUNK, NN);
    int pm = pad - 1;
    int s = 0;
    for (int i = begin; i < end; ++i) s += (counts[i] + pm) & ~pm;
    part[tid] = s;
    __syncthreads();
    for (int off = 1; off < SCAN_THREADS; off <<= 1) {
        int v = (tid >= off) ? part[tid - off] : 0;
        __syncthreads();
        part[tid] += v;
        __syncthreads();
    }
    int run = (tid == 0) ? 0 : part[tid - 1];
    for (int i = begin; i < end; ++i) {
        offsets[i] = run;
        cursor[i]  = run;
        run += (counts[i] + pm) & ~pm;
    }
    if (tid == SCAN_THREADS - 1) offsets[NN] = part[SCAN_THREADS - 1];
}

// Node-parallel NaN-sentinel pad writes (fmaxf(acc, NaN*v) == acc on v_max_f32).
__global__ void k_pad(const int* __restrict__ counts, const int* __restrict__ offsets,
                      int* __restrict__ esrc, float* __restrict__ ew) {
    int n = blockIdx.x * blockDim.x + threadIdx.x;
    if (n >= NN) return;
    int d    = counts[n];
    int beg  = offsets[n];
    int pdeg = (d + 3) & ~3;
    const float qnan = __int_as_float(0x7FC00000);
    for (int p = beg + d; p < beg + pdeg; ++p) { esrc[p] = 0; ew[p] = qnan; }
}

__global__ void k_scatter(const int* __restrict__ src, const int* __restrict__ dst,
                          const float* __restrict__ w,
                          int* __restrict__ cursor,
                          int* __restrict__ esrc, float* __restrict__ ew) {
    int e = blockIdx.x * blockDim.x + threadIdx.x;
    if (e >= NE) return;
    int d = dst[e];
    int pos = atomicAdd(&cursor[d], 1);
    esrc[pos] = src[e];
    ew[pos]   = w[e];
}

// ---------------- main gather-max ----------------
// One block = (bt pair {bt0, bt0+48}, 64-node chunk). 256 thr = 64 nodes x 4 d4.
// XCD pinning: idx%8 = XCD -> 1.28 MB V pair stays L2-resident.
// PADDED: rows pad-to-4 with NaN sentinels; beg is 4-aligned so edge ids and
// weights load as one int4 + one float4 (cuts 8 scalar VMEM -> 2 per iter).
template <bool PADDED>
__global__ __launch_bounds__(256) void k_main(const float* __restrict__ V,
                                              const int* __restrict__ offsets,
                                              const int* __restrict__ esrc,
                                              const float* __restrict__ ew,
                                              float* __restrict__ out) {
    int idx = blockIdx.x;
    int r   = idx & 7;
    int k   = idx >> 3;
    int btd = k / NCHUNK;             // 0..5
    int chunk = k - btd * NCHUNK;     // 0..156
    int bt0 = r + 8 * btd;            // 0..47
    int bt1 = bt0 + 48;               // 48..95

    int tid = threadIdx.x;
    int n   = chunk * NODES_PER_BLOCK + (tid >> 2);
    int d4  = (tid & 3) << 2;
    if (n >= NN) return;              // no LDS/sync: early-exit safe

    const float* __restrict__ Va = V + (size_t)bt0 * (NN * DD) + d4;
    const float* __restrict__ Vb = V + (size_t)bt1 * (NN * DD) + d4;

    int beg  = offsets[n];
    int endo = offsets[n + 1];

    const float ninf = -__builtin_huge_valf();
    float4 accA = {ninf, ninf, ninf, ninf};
    float4 accB = {ninf, ninf, ninf, ninf};

    int j = beg;
    for (; j + 4 <= endo; j += 4) {
        int4   ss = *reinterpret_cast<const int4*>(esrc + j);
        float4 wwv = *reinterpret_cast<const float4*>(ew + j);
        float4 a0 = *reinterpret_cast<const float4*>(Va + ss.x * DD);
        float4 a1 = *reinterpret_cast<const float4*>(Va + ss.y * DD);
        float4 a2 = *reinterpret_cast<const float4*>(Va + ss.z * DD);
        float4 a3 = *reinterpret_cast<const float4*>(Va + ss.w * DD);
        float4 b0 = *reinterpret_cast<const float4*>(Vb + ss.x * DD);
        float4 b1 = *reinterpret_cast<const float4*>(Vb + ss.y * DD);
        float4 b2 = *reinterpret_cast<const float4*>(Vb + ss.z * DD);
        float4 b3 = *reinterpret_cast<const float4*>(Vb + ss.w * DD);
        accA.x = fmaxf(accA.x, fmaxf(fmaxf(a0.x*wwv.x, a1.x*wwv.y), fmaxf(a2.x*wwv.z, a3.x*wwv.w)));
        accA.y = fmaxf(accA.y, fmaxf(fmaxf(a0.y*wwv.x, a1.y*wwv.y), fmaxf(a2.y*wwv.z, a3.y*wwv.w)));
        accA.z = fmaxf(accA.z, fmaxf(fmaxf(a0.z*wwv.x, a1.z*wwv.y), fmaxf(a2.z*wwv.z, a3.z*wwv.w)));
        accA.w = fmaxf(accA.w, fmaxf(fmaxf(a0.w*wwv.x, a1.w*wwv.y), fmaxf(a2.w*wwv.z, a3.w*wwv.w)));
        accB.x = fmaxf(accB.x, fmaxf(fmaxf(b0.x*wwv.x, b1.x*wwv.y), fmaxf(b2.x*wwv.z, b3.x*wwv.w)));
        accB.y = fmaxf(accB.y, fmaxf(fmaxf(b0.y*wwv.x, b1.y*wwv.y), fmaxf(b2.y*wwv.z, b3.y*wwv.w)));
        accB.z = fmaxf(accB.z, fmaxf(fmaxf(b0.z*wwv.x, b1.z*wwv.y), fmaxf(b2.z*wwv.z, b3.z*wwv.w)));
        accB.w = fmaxf(accB.w, fmaxf(fmaxf(b0.w*wwv.x, b1.w*wwv.y), fmaxf(b2.w*wwv.z, b3.w*wwv.w)));
    }
    if (!PADDED) {
        for (; j < endo; ++j) {
            int   s  = esrc[j];
            float we = ew[j];
            float4 a = *reinterpret_cast<const float4*>(Va + s * DD);
            float4 b = *reinterpret_cast<const float4*>(Vb + s * DD);
            accA.x = fmaxf(accA.x, a.x * we);
            accA.y = fmaxf(accA.y, a.y * we);
            accA.z = fmaxf(accA.z, a.z * we);
            accA.w = fmaxf(accA.w, a.w * we);
            accB.x = fmaxf(accB.x, b.x * we);
            accB.y = fmaxf(accB.y, b.y * we);
            accB.z = fmaxf(accB.z, b.z * we);
            accB.w = fmaxf(accB.w, b.w * we);
        }
    }

    float4 ra, rb;
    ra.x = (accA.x == ninf) ? 0.0f : accA.x;
    ra.y = (accA.y == ninf) ? 0.0f : accA.y;
    ra.z = (accA.z == ninf) ? 0.0f : accA.z;
    ra.w = (accA.w == ninf) ? 0.0f : accA.w;
    rb.x = (accB.x == ninf) ? 0.0f : accB.x;
    rb.y = (accB.y == ninf) ? 0.0f : accB.y;
    rb.z = (accB.z == ninf) ? 0.0f : accB.z;
    rb.w = (accB.w == ninf) ? 0.0f : accB.w;
    *reinterpret_cast<float4*>(out + ((size_t)bt0 * NN + n) * DD + d4) = ra;
    *reinterpret_cast<float4*>(out + ((size_t)bt1 * NN + n) * DD + d4) = rb;
}

// ---------------- launch ----------------

extern "C" void kernel_launch(void* const* d_in, const int* in_sizes, int n_in,
                              void* d_out, int out_size, void* d_ws, size_t ws_size,
                              hipStream_t stream) {
    const float* V   = (const float*)d_in[0];
    const int*   src = (const int*)d_in[1];
    const int*   dst = (const int*)d_in[2];
    const float* w   = (const float*)d_in[3];
    float* out = (float*)d_out;

    int nblocks = NXCD * BTD_MAX * NCHUNK;   // 7536

    // ws layout (4B elems), esrc/ew 16B-aligned:
    // esrc[NEP] | ew[NEP] | counts[NN] | offsets[NN+1] | cursor[NN]
    size_t need = (size_t)(2 * NEP + 3 * NN + 1) * 4;
    int* ws_i = (int*)d_ws;
    int*   esrc    = ws_i;
    float* ew      = (float*)(ws_i + NEP);
    int*   counts  = ws_i + 2 * NEP;
    int*   offsets = counts + NN;
    int*   cursor  = offsets + NN + 1;

    bool padded = ws_size >= need;

    hipMemsetAsync(counts, 0, NN * sizeof(int), stream);
    k_hist<<<(NE + 255) / 256, 256, 0, stream>>>(dst, counts);
    k_scan<<<1, SCAN_THREADS, 0, stream>>>(counts, offsets, cursor, padded ? 4 : 1);
    if (padded) {
        k_pad<<<(NN + 255) / 256, 256, 0, stream>>>(counts, offsets, esrc, ew);
        k_scatter<<<(NE + 255) / 256, 256, 0, stream>>>(src, dst, w, cursor, esrc, ew);
        k_main<true><<<nblocks, 256, 0, stream>>>(V, offsets, esrc, ew, out);
    } else {
        k_scatter<<<(NE + 255) / 256, 256, 0, stream>>>(src, dst, w, cursor, esrc, ew);
        k_main<false><<<nblocks, 256, 0, stream>>>(V, offsets, esrc, ew, out);
    }
}

// Round 10
// 127.546 us; speedup vs baseline: 1.3352x; 1.0396x over previous
//
#include <hip/hip_runtime.h>

// Problem constants: B=8, T=12 (BT=96), N=10000, D=16, E=160000
#define NN  10000
#define NE  160000
#define NBT 96
#define DD  16

#define SCAN_THREADS 1024
#define SCHUNK 10                 // ceil(NN / SCAN_THREADS)

#define NODES_PER_BLOCK 64
#define NCHUNK 157                // ceil(NN / NODES_PER_BLOCK)
#define NXCD 8
#define BTD_MAX 6                 // thread handles bt and bt+48

#define NEP 190000                // >= NE + 3*NN, 16B-aligned element count

// ---------------- CSR build ----------------

__global__ void k_hist(const int* __restrict__ dst, int* __restrict__ counts) {
    int e = blockIdx.x * blockDim.x + threadIdx.x;
    if (e < NE) atomicAdd(&counts[dst[e]], 1);
}

// Single-block exclusive scan of pad-to-4 degrees -> offsets/cursor.
__global__ __launch_bounds__(SCAN_THREADS) void k_scan(const int* __restrict__ counts,
                                                       int* __restrict__ offsets,
                                                       int* __restrict__ cursor,
                                                       int pad) {
    __shared__ int part[SCAN_THREADS];
    int tid = threadIdx.x;
    int begin = tid * SCHUNK;
    int end   = min(begin + SCHUNK, NN);
    int pm = pad - 1;
    int s = 0;
    for (int i = begin; i < end; ++i) s += (counts[i] + pm) & ~pm;
    part[tid] = s;
    __syncthreads();
    for (int off = 1; off < SCAN_THREADS; off <<= 1) {
        int v = (tid >= off) ? part[tid - off] : 0;
        __syncthreads();
        part[tid] += v;
        __syncthreads();
    }
    int run = (tid == 0) ? 0 : part[tid - 1];
    for (int i = begin; i < end; ++i) {
        offsets[i] = run;
        cursor[i]  = run;
        run += (counts[i] + pm) & ~pm;
    }
    if (tid == SCAN_THREADS - 1) offsets[NN] = part[SCAN_THREADS - 1];
}

// Fused: blocks [0, SCAT_BLK) scatter edges; blocks [SCAT_BLK, ..) write NaN
// sentinels into the pad region (fmaxf(acc, NaN*v) == acc on v_max_f32).
#define SCAT_BLK 625              // ceil(NE/256)
__global__ void k_scatter_pad(const int* __restrict__ src, const int* __restrict__ dst,
                              const float* __restrict__ w,
                              const int* __restrict__ counts,
                              const int* __restrict__ offsets,
                              int* __restrict__ cursor,
                              int* __restrict__ esrc, float* __restrict__ ew) {
    int b = blockIdx.x;
    if (b < SCAT_BLK) {
        int e = b * blockDim.x + threadIdx.x;
        if (e >= NE) return;
        int d = dst[e];
        int pos = atomicAdd(&cursor[d], 1);
        esrc[pos] = src[e];
        ew[pos]   = w[e];
    } else {
        int n = (b - SCAT_BLK) * blockDim.x + threadIdx.x;
        if (n >= NN) return;
        int d    = counts[n];
        int beg  = offsets[n];
        int pdeg = (d + 3) & ~3;
        const float qnan = __int_as_float(0x7FC00000);
        for (int p = beg + d; p < beg + pdeg; ++p) { esrc[p] = 0; ew[p] = qnan; }
    }
}

// ---------------- main gather-max ----------------
// One block = (bt pair {bt0, bt0+48}, 64-node chunk). 256 thr = 64 nodes x 4 d4.
// XCD pinning: idx%8 = XCD -> 1.28 MB V pair stays L2-resident.
// 2-deep software pipeline; edge loads for stage t+2 are issued BEFORE the
// gathers of stage t+1 so consuming stage t waits only its own 8 gathers
// (vmcnt is in-order).

struct Regs {
    float4 a0, a1, a2, a3, b0, b1, b2, b3;
};

__device__ __forceinline__ void gather(Regs& g, const float* __restrict__ Va,
                                       const float* __restrict__ Vb, int4 ss) {
    g.a0 = *reinterpret_cast<const float4*>(Va + ss.x * DD);
    g.a1 = *reinterpret_cast<const float4*>(Va + ss.y * DD);
    g.a2 = *reinterpret_cast<const float4*>(Va + ss.z * DD);
    g.a3 = *reinterpret_cast<const float4*>(Va + ss.w * DD);
    g.b0 = *reinterpret_cast<const float4*>(Vb + ss.x * DD);
    g.b1 = *reinterpret_cast<const float4*>(Vb + ss.y * DD);
    g.b2 = *reinterpret_cast<const float4*>(Vb + ss.z * DD);
    g.b3 = *reinterpret_cast<const float4*>(Vb + ss.w * DD);
}

__device__ __forceinline__ void consume(const Regs& g, float4 wv,
                                        float4& accA, float4& accB) {
    accA.x = fmaxf(accA.x, fmaxf(fmaxf(g.a0.x*wv.x, g.a1.x*wv.y), fmaxf(g.a2.x*wv.z, g.a3.x*wv.w)));
    accA.y = fmaxf(accA.y, fmaxf(fmaxf(g.a0.y*wv.x, g.a1.y*wv.y), fmaxf(g.a2.y*wv.z, g.a3.y*wv.w)));
    accA.z = fmaxf(accA.z, fmaxf(fmaxf(g.a0.z*wv.x, g.a1.z*wv.y), fmaxf(g.a2.z*wv.z, g.a3.z*wv.w)));
    accA.w = fmaxf(accA.w, fmaxf(fmaxf(g.a0.w*wv.x, g.a1.w*wv.y), fmaxf(g.a2.w*wv.z, g.a3.w*wv.w)));
    accB.x = fmaxf(accB.x, fmaxf(fmaxf(g.b0.x*wv.x, g.b1.x*wv.y), fmaxf(g.b2.x*wv.z, g.b3.x*wv.w)));
    accB.y = fmaxf(accB.y, fmaxf(fmaxf(g.b0.y*wv.x, g.b1.y*wv.y), fmaxf(g.b2.y*wv.z, g.b3.y*wv.w)));
    accB.z = fmaxf(accB.z, fmaxf(fmaxf(g.b0.z*wv.x, g.b1.z*wv.y), fmaxf(g.b2.z*wv.z, g.b3.z*wv.w)));
    accB.w = fmaxf(accB.w, fmaxf(fmaxf(g.b0.w*wv.x, g.b1.w*wv.y), fmaxf(g.b2.w*wv.z, g.b3.w*wv.w)));
}

template <bool PADDED>
__global__ __launch_bounds__(256) void k_main(const float* __restrict__ V,
                                              const int* __restrict__ offsets,
                                              const int* __restrict__ esrc,
                                              const float* __restrict__ ew,
                                              float* __restrict__ out) {
    int idx = blockIdx.x;
    int r   = idx & 7;
    int k   = idx >> 3;
    int btd = k / NCHUNK;             // 0..5
    int chunk = k - btd * NCHUNK;     // 0..156
    int bt0 = r + 8 * btd;            // 0..47
    int bt1 = bt0 + 48;               // 48..95

    int tid = threadIdx.x;
    int n   = chunk * NODES_PER_BLOCK + (tid >> 2);
    int d4  = (tid & 3) << 2;
    if (n >= NN) return;              // no LDS/sync: early-exit safe

    const float* __restrict__ Va = V + (size_t)bt0 * (NN * DD) + d4;
    const float* __restrict__ Vb = V + (size_t)bt1 * (NN * DD) + d4;

    int beg  = offsets[n];
    int endo = offsets[n + 1];

    const float ninf = -__builtin_huge_valf();
    float4 accA = {ninf, ninf, ninf, ninf};
    float4 accB = {ninf, ninf, ninf, ninf};

    if (PADDED) {
        int trips = (endo - beg) >> 2;
        if (trips > 0) {
            const int4*   ep = reinterpret_cast<const int4*>(esrc + beg);
            const float4* wp = reinterpret_cast<const float4*>(ew + beg);

            Regs g0, g1;

            int4 ss0 = ep[0]; float4 ww0 = wp[0];
            int4 ss1 = ss0;   float4 ww1 = ww0;
            if (trips > 1) { ss1 = ep[1]; ww1 = wp[1]; }
            gather(g0, Va, Vb, ss0);

            int t = 0;
            for (; t + 2 < trips; t += 2) {
                // consume stage t (g0), issue gathers t+1, prefetch edge t+2
                float4 wc0 = ww0;
                ss0 = ep[t+2]; ww0 = wp[t+2];        // edge t+2 in flight (before gathers t+1)
                gather(g1, Va, Vb, ss1);             // gathers t+1
                consume(g0, wc0, accA, accB);        // waits gathers t only
                // consume stage t+1 (g1), issue gathers t+2, prefetch edge t+3
                float4 wc1 = ww1;
                if (t + 3 < trips) { ss1 = ep[t+3]; ww1 = wp[t+3]; }
                gather(g0, Va, Vb, ss0);             // gathers t+2
                consume(g1, wc1, accA, accB);        // waits gathers t+1 only
            }
            if (t + 1 < trips) {                     // two stages left: t (g0), t+1 (ss1)
                gather(g1, Va, Vb, ss1);
                consume(g0, ww0, accA, accB);
                consume(g1, ww1, accA, accB);
            } else {                                 // one stage left: t (g0)
                consume(g0, ww0, accA, accB);
            }
        }
    } else {
        for (int j = beg; j < endo; ++j) {
            int   s  = esrc[j];
            float we = ew[j];
            float4 a = *reinterpret_cast<const float4*>(Va + s * DD);
            float4 b = *reinterpret_cast<const float4*>(Vb + s * DD);
            accA.x = fmaxf(accA.x, a.x * we);
            accA.y = fmaxf(accA.y, a.y * we);
            accA.z = fmaxf(accA.z, a.z * we);
            accA.w = fmaxf(accA.w, a.w * we);
            accB.x = fmaxf(accB.x, b.x * we);
            accB.y = fmaxf(accB.y, b.y * we);
            accB.z = fmaxf(accB.z, b.z * we);
            accB.w = fmaxf(accB.w, b.w * we);
        }
    }

    float4 ra, rb;
    ra.x = (accA.x == ninf) ? 0.0f : accA.x;
    ra.y = (accA.y == ninf) ? 0.0f : accA.y;
    ra.z = (accA.z == ninf) ? 0.0f : accA.z;
    ra.w = (accA.w == ninf) ? 0.0f : accA.w;
    rb.x = (accB.x == ninf) ? 0.0f : accB.x;
    rb.y = (accB.y == ninf) ? 0.0f : accB.y;
    rb.z = (accB.z == ninf) ? 0.0f : accB.z;
    rb.w = (accB.w == ninf) ? 0.0f : accB.w;
    *reinterpret_cast<float4*>(out + ((size_t)bt0 * NN + n) * DD + d4) = ra;
    *reinterpret_cast<float4*>(out + ((size_t)bt1 * NN + n) * DD + d4) = rb;
}

// ---------------- launch ----------------

extern "C" void kernel_launch(void* const* d_in, const int* in_sizes, int n_in,
                              void* d_out, int out_size, void* d_ws, size_t ws_size,
                              hipStream_t stream) {
    const float* V   = (const float*)d_in[0];
    const int*   src = (const int*)d_in[1];
    const int*   dst = (const int*)d_in[2];
    const float* w   = (const float*)d_in[3];
    float* out = (float*)d_out;

    int nblocks = NXCD * BTD_MAX * NCHUNK;   // 7536

    // ws layout (4B elems), esrc/ew 16B-aligned:
    // esrc[NEP] | ew[NEP] | counts[NN] | offsets[NN+1] | cursor[NN]
    size_t need = (size_t)(2 * NEP + 3 * NN + 1) * 4;
    int* ws_i = (int*)d_ws;
    int*   esrc    = ws_i;
    float* ew      = (float*)(ws_i + NEP);
    int*   counts  = ws_i + 2 * NEP;
    int*   offsets = counts + NN;
    int*   cursor  = offsets + NN + 1;

    bool padded = ws_size >= need;

    (void)hipMemsetAsync(counts, 0, NN * sizeof(int), stream);
    k_hist<<<(NE + 255) / 256, 256, 0, stream>>>(dst, counts);
    k_scan<<<1, SCAN_THREADS, 0, stream>>>(counts, offsets, cursor, padded ? 4 : 1);
    if (padded) {
        int pad_blk = (NN + 255) / 256;      // 40
        k_scatter_pad<<<SCAT_BLK + pad_blk, 256, 0, stream>>>(src, dst, w, counts,
                                                              offsets, cursor, esrc, ew);
        k_main<true><<<nblocks, 256, 0, stream>>>(V, offsets, esrc, ew, out);
    } else {
        k_scatter_pad<<<SCAT_BLK, 256, 0, stream>>>(src, dst, w, counts,
                                                    offsets, cursor, esrc, ew);
        k_main<false><<<nblocks, 256, 0, stream>>>(V, offsets, esrc, ew, out);
    }
}

// Round 11
// 114.269 us; speedup vs baseline: 1.4903x; 1.1162x over previous
//
#include <hip/hip_runtime.h>

// Problem constants: B=8, T=12 (BT=96), N=10000, D=16, E=160000
#define NN  10000
#define NE  160000
#define NBT 96
#define DD  16

#define NODES_PER_BLOCK 64
#define NCHUNK 157                // ceil(NN / NODES_PER_BLOCK)
#define NXCD 8
#define BTD_MAX 6                 // thread handles bt and bt+48

// ---- direct fixed-stride edge rows ----
#define STRIDE 64                 // max supported in-degree (Poisson(16): P(>=64) ~ 1e-18)
#define NROW (NN * STRIDE)        // 640000 elements per array

// ---- CSR fallback constants (round-7 proven path) ----
#define SCAN_THREADS 1024
#define SCHUNK 10
#define NEP 190000
#define SCAT_BLK 625

// ================= direct path =================

// One launch: zero esrc, NaN-fill ew (0xFFFFFFFF is a NaN; fmaxf(acc, NaN*v)==acc
// on v_max_f32), zero cnt.
__global__ void k_init(int* __restrict__ esrc, float* __restrict__ ew,
                       int* __restrict__ cnt) {
    int i = blockIdx.x * blockDim.x + threadIdx.x;
    const int tot = NROW / 4;     // 160000 uint4 per array
    uint4 z  = {0u, 0u, 0u, 0u};
    uint4 qn = {0xFFFFFFFFu, 0xFFFFFFFFu, 0xFFFFFFFFu, 0xFFFFFFFFu};
    int stridew = gridDim.x * blockDim.x;
    for (int p = i; p < tot; p += stridew) {
        reinterpret_cast<uint4*>(esrc)[p] = z;
        reinterpret_cast<uint4*>(ew)[p]   = qn;
    }
    if (i < NN) cnt[i] = 0;
}

__global__ void k_scat(const int* __restrict__ src, const int* __restrict__ dst,
                       const float* __restrict__ w,
                       int* __restrict__ cnt,
                       int* __restrict__ esrc, float* __restrict__ ew) {
    int e = blockIdx.x * blockDim.x + threadIdx.x;
    if (e >= NE) return;
    int d   = dst[e];
    int pos = atomicAdd(&cnt[d], 1);
    if (pos < STRIDE) {           // safety clamp (prob ~0 on this dataset)
        int q = d * STRIDE + pos;
        esrc[q] = src[e];
        ew[q]   = w[e];
    }
}

// ================= CSR fallback build =================

__global__ void k_hist(const int* __restrict__ dst, int* __restrict__ counts) {
    int e = blockIdx.x * blockDim.x + threadIdx.x;
    if (e < NE) atomicAdd(&counts[dst[e]], 1);
}

__global__ __launch_bounds__(SCAN_THREADS) void k_scan(const int* __restrict__ counts,
                                                       int* __restrict__ offsets,
                                                       int* __restrict__ cursor,
                                                       int pad) {
    __shared__ int part[SCAN_THREADS];
    int tid = threadIdx.x;
    int begin = tid * SCHUNK;
    int end   = min(begin + SCHUNK, NN);
    int pm = pad - 1;
    int s = 0;
    for (int i = begin; i < end; ++i) s += (counts[i] + pm) & ~pm;
    part[tid] = s;
    __syncthreads();
    for (int off = 1; off < SCAN_THREADS; off <<= 1) {
        int v = (tid >= off) ? part[tid - off] : 0;
        __syncthreads();
        part[tid] += v;
        __syncthreads();
    }
    int run = (tid == 0) ? 0 : part[tid - 1];
    for (int i = begin; i < end; ++i) {
        offsets[i] = run;
        cursor[i]  = run;
        run += (counts[i] + pm) & ~pm;
    }
    if (tid == SCAN_THREADS - 1) offsets[NN] = part[SCAN_THREADS - 1];
}

__global__ void k_scatter_pad(const int* __restrict__ src, const int* __restrict__ dst,
                              const float* __restrict__ w,
                              const int* __restrict__ counts,
                              const int* __restrict__ offsets,
                              int* __restrict__ cursor,
                              int* __restrict__ esrc, float* __restrict__ ew) {
    int b = blockIdx.x;
    if (b < SCAT_BLK) {
        int e = b * blockDim.x + threadIdx.x;
        if (e >= NE) return;
        int d = dst[e];
        int pos = atomicAdd(&cursor[d], 1);
        esrc[pos] = src[e];
        ew[pos]   = w[e];
    } else {
        int n = (b - SCAT_BLK) * blockDim.x + threadIdx.x;
        if (n >= NN) return;
        int d    = counts[n];
        int beg  = offsets[n];
        int pdeg = (d + 3) & ~3;
        const float qnan = __int_as_float(0x7FC00000);
        for (int p = beg + d; p < beg + pdeg; ++p) { esrc[p] = 0; ew[p] = qnan; }
    }
}

// ================= main gather-max =================
// One block = (bt pair {bt0, bt0+48}, 64-node chunk). 256 thr = 64 nodes x 4 d4.
// XCD pinning: idx%8 = XCD -> 1.28 MB V pair stays L2-resident.
// 2-deep software pipeline; edge loads for stage t+2 are issued BEFORE the
// gathers of stage t+1 so consuming stage t waits only its own 8 gathers.
// MODE 0: fixed-stride rows (meta = per-node count). MODE 1: CSR padded
// (meta = offsets). MODE 2: CSR unpadded scalar loop.

struct Regs {
    float4 a0, a1, a2, a3, b0, b1, b2, b3;
};

__device__ __forceinline__ void gather(Regs& g, const float* __restrict__ Va,
                                       const float* __restrict__ Vb, int4 ss) {
    g.a0 = *reinterpret_cast<const float4*>(Va + ss.x * DD);
    g.a1 = *reinterpret_cast<const float4*>(Va + ss.y * DD);
    g.a2 = *reinterpret_cast<const float4*>(Va + ss.z * DD);
    g.a3 = *reinterpret_cast<const float4*>(Va + ss.w * DD);
    g.b0 = *reinterpret_cast<const float4*>(Vb + ss.x * DD);
    g.b1 = *reinterpret_cast<const float4*>(Vb + ss.y * DD);
    g.b2 = *reinterpret_cast<const float4*>(Vb + ss.z * DD);
    g.b3 = *reinterpret_cast<const float4*>(Vb + ss.w * DD);
}

__device__ __forceinline__ void consume(const Regs& g, float4 wv,
                                        float4& accA, float4& accB) {
    accA.x = fmaxf(accA.x, fmaxf(fmaxf(g.a0.x*wv.x, g.a1.x*wv.y), fmaxf(g.a2.x*wv.z, g.a3.x*wv.w)));
    accA.y = fmaxf(accA.y, fmaxf(fmaxf(g.a0.y*wv.x, g.a1.y*wv.y), fmaxf(g.a2.y*wv.z, g.a3.y*wv.w)));
    accA.z = fmaxf(accA.z, fmaxf(fmaxf(g.a0.z*wv.x, g.a1.z*wv.y), fmaxf(g.a2.z*wv.z, g.a3.z*wv.w)));
    accA.w = fmaxf(accA.w, fmaxf(fmaxf(g.a0.w*wv.x, g.a1.w*wv.y), fmaxf(g.a2.w*wv.z, g.a3.w*wv.w)));
    accB.x = fmaxf(accB.x, fmaxf(fmaxf(g.b0.x*wv.x, g.b1.x*wv.y), fmaxf(g.b2.x*wv.z, g.b3.x*wv.w)));
    accB.y = fmaxf(accB.y, fmaxf(fmaxf(g.b0.y*wv.x, g.b1.y*wv.y), fmaxf(g.b2.y*wv.z, g.b3.y*wv.w)));
    accB.z = fmaxf(accB.z, fmaxf(fmaxf(g.b0.z*wv.x, g.b1.z*wv.y), fmaxf(g.b2.z*wv.z, g.b3.z*wv.w)));
    accB.w = fmaxf(accB.w, fmaxf(fmaxf(g.b0.w*wv.x, g.b1.w*wv.y), fmaxf(g.b2.w*wv.z, g.b3.w*wv.w)));
}

template <int MODE>
__global__ __launch_bounds__(256) void k_main(const float* __restrict__ V,
                                              const int* __restrict__ meta,
                                              const int* __restrict__ esrc,
                                              const float* __restrict__ ew,
                                              float* __restrict__ out) {
    int idx = blockIdx.x;
    int r   = idx & 7;
    int k   = idx >> 3;
    int btd = k / NCHUNK;             // 0..5
    int chunk = k - btd * NCHUNK;     // 0..156
    int bt0 = r + 8 * btd;            // 0..47
    int bt1 = bt0 + 48;               // 48..95

    int tid = threadIdx.x;
    int n   = chunk * NODES_PER_BLOCK + (tid >> 2);
    int d4  = (tid & 3) << 2;
    if (n >= NN) return;              // no LDS/sync: early-exit safe

    const float* __restrict__ Va = V + (size_t)bt0 * (NN * DD) + d4;
    const float* __restrict__ Vb = V + (size_t)bt1 * (NN * DD) + d4;

    const float ninf = -__builtin_huge_valf();
    float4 accA = {ninf, ninf, ninf, ninf};
    float4 accB = {ninf, ninf, ninf, ninf};

    if (MODE == 0 || MODE == 1) {
        int beg, trips;
        if (MODE == 0) {
            beg   = n * STRIDE;
            int d = meta[n];
            trips = (d + 3) >> 2;     // pad slots are NaN-filled by k_init
        } else {
            beg   = meta[n];
            trips = (meta[n + 1] - beg) >> 2;
        }
        if (trips > 0) {
            const int4*   ep = reinterpret_cast<const int4*>(esrc + beg);
            const float4* wp = reinterpret_cast<const float4*>(ew + beg);

            Regs g0, g1;

            int4 ss0 = ep[0]; float4 ww0 = wp[0];
            int4 ss1 = ss0;   float4 ww1 = ww0;
            if (trips > 1) { ss1 = ep[1]; ww1 = wp[1]; }
            gather(g0, Va, Vb, ss0);

            int t = 0;
            for (; t + 2 < trips; t += 2) {
                float4 wc0 = ww0;
                ss0 = ep[t+2]; ww0 = wp[t+2];        // edge t+2 in flight first
                gather(g1, Va, Vb, ss1);             // gathers t+1
                consume(g0, wc0, accA, accB);        // waits gathers t only
                float4 wc1 = ww1;
                if (t + 3 < trips) { ss1 = ep[t+3]; ww1 = wp[t+3]; }
                gather(g0, Va, Vb, ss0);             // gathers t+2
                consume(g1, wc1, accA, accB);        // waits gathers t+1 only
            }
            if (t + 1 < trips) {
                gather(g1, Va, Vb, ss1);
                consume(g0, ww0, accA, accB);
                consume(g1, ww1, accA, accB);
            } else {
                consume(g0, ww0, accA, accB);
            }
        }
    } else {
        int beg = meta[n], endo = meta[n + 1];
        for (int j = beg; j < endo; ++j) {
            int   s  = esrc[j];
            float we = ew[j];
            float4 a = *reinterpret_cast<const float4*>(Va + s * DD);
            float4 b = *reinterpret_cast<const float4*>(Vb + s * DD);
            accA.x = fmaxf(accA.x, a.x * we);
            accA.y = fmaxf(accA.y, a.y * we);
            accA.z = fmaxf(accA.z, a.z * we);
            accA.w = fmaxf(accA.w, a.w * we);
            accB.x = fmaxf(accB.x, b.x * we);
            accB.y = fmaxf(accB.y, b.y * we);
            accB.z = fmaxf(accB.z, b.z * we);
            accB.w = fmaxf(accB.w, b.w * we);
        }
    }

    float4 ra, rb;
    ra.x = (accA.x == ninf) ? 0.0f : accA.x;
    ra.y = (accA.y == ninf) ? 0.0f : accA.y;
    ra.z = (accA.z == ninf) ? 0.0f : accA.z;
    ra.w = (accA.w == ninf) ? 0.0f : accA.w;
    rb.x = (accB.x == ninf) ? 0.0f : accB.x;
    rb.y = (accB.y == ninf) ? 0.0f : accB.y;
    rb.z = (accB.z == ninf) ? 0.0f : accB.z;
    rb.w = (accB.w == ninf) ? 0.0f : accB.w;
    *reinterpret_cast<float4*>(out + ((size_t)bt0 * NN + n) * DD + d4) = ra;
    *reinterpret_cast<float4*>(out + ((size_t)bt1 * NN + n) * DD + d4) = rb;
}

// ================= launch =================

extern "C" void kernel_launch(void* const* d_in, const int* in_sizes, int n_in,
                              void* d_out, int out_size, void* d_ws, size_t ws_size,
                              hipStream_t stream) {
    const float* V   = (const float*)d_in[0];
    const int*   src = (const int*)d_in[1];
    const int*   dst = (const int*)d_in[2];
    const float* w   = (const float*)d_in[3];
    float* out = (float*)d_out;

    int nblocks = NXCD * BTD_MAX * NCHUNK;   // 7536
    int* ws_i = (int*)d_ws;

    // direct path ws layout (4B elems, 16B-aligned): esrc[NROW] | ew[NROW] | cnt[NN]
    size_t need_direct = (size_t)(2 * NROW + NN) * 4;

    if (ws_size >= need_direct) {
        int*   esrc = ws_i;
        float* ew   = (float*)(ws_i + NROW);
        int*   cnt  = ws_i + 2 * NROW;

        k_init<<<1280, 256, 0, stream>>>(esrc, ew, cnt);
        k_scat<<<(NE + 255) / 256, 256, 0, stream>>>(src, dst, w, cnt, esrc, ew);
        k_main<0><<<nblocks, 256, 0, stream>>>(V, cnt, esrc, ew, out);
        return;
    }

    // CSR fallback: esrc[NEP] | ew[NEP] | counts[NN] | offsets[NN+1] | cursor[NN]
    size_t need_csr = (size_t)(2 * NEP + 3 * NN + 1) * 4;
    int*   esrc    = ws_i;
    float* ew      = (float*)(ws_i + NEP);
    int*   counts  = ws_i + 2 * NEP;
    int*   offsets = counts + NN;
    int*   cursor  = offsets + NN + 1;

    bool padded = ws_size >= need_csr;

    (void)hipMemsetAsync(counts, 0, NN * sizeof(int), stream);
    k_hist<<<(NE + 255) / 256, 256, 0, stream>>>(dst, counts);
    k_scan<<<1, SCAN_THREADS, 0, stream>>>(counts, offsets, cursor, padded ? 4 : 1);
    if (padded) {
        int pad_blk = (NN + 255) / 256;
        k_scatter_pad<<<SCAT_BLK + pad_blk, 256, 0, stream>>>(src, dst, w, counts,
                                                              offsets, cursor, esrc, ew);
        k_main<1><<<nblocks, 256, 0, stream>>>(V, offsets, esrc, ew, out);
    } else {
        k_scatter_pad<<<SCAT_BLK, 256, 0, stream>>>(src, dst, w, counts,
                                                    offsets, cursor, esrc, ew);
        k_main<2><<<nblocks, 256, 0, stream>>>(V, offsets, esrc, ew, out);
    }
}

// Round 12
// 114.263 us; speedup vs baseline: 1.4904x; 1.0001x over previous
//
#include <hip/hip_runtime.h>

// Problem constants: B=8, T=12 (BT=96), N=10000, D=16, E=160000
#define NN  10000
#define NE  160000
#define NBT 96
#define DD  16

#define NODES_PER_BLOCK 64
#define NCHUNK 157                // ceil(NN / NODES_PER_BLOCK)
#define NXCD 8
#define BTD_MAX 6                 // thread handles bt and bt+48

// ---- direct fixed-stride edge rows ----
#define STRIDE 64                 // max supported in-degree (Poisson(16): P(>=64) ~ 1e-18)
#define NROW (NN * STRIDE)        // 640000 elements per array
#define NPERM (NCHUNK * 64)       // 10048

// ---- CSR fallback constants (round-7 proven path) ----
#define SCAN_THREADS 1024
#define SCHUNK 10
#define NEP 190000
#define SCAT_BLK 625

// ================= direct path =================

__global__ void k_init(int* __restrict__ esrc, float* __restrict__ ew,
                       int* __restrict__ cnt) {
    int i = blockIdx.x * blockDim.x + threadIdx.x;
    const int tot = NROW / 4;     // 160000 uint4 per array
    uint4 z  = {0u, 0u, 0u, 0u};
    uint4 qn = {0xFFFFFFFFu, 0xFFFFFFFFu, 0xFFFFFFFFu, 0xFFFFFFFFu}; // NaN bits
    int stridew = gridDim.x * blockDim.x;
    for (int p = i; p < tot; p += stridew) {
        reinterpret_cast<uint4*>(esrc)[p] = z;
        reinterpret_cast<uint4*>(ew)[p]   = qn;
    }
    if (i < NN) cnt[i] = 0;
}

__global__ void k_scat(const int* __restrict__ src, const int* __restrict__ dst,
                       const float* __restrict__ w,
                       int* __restrict__ cnt,
                       int* __restrict__ esrc, float* __restrict__ ew) {
    int e = blockIdx.x * blockDim.x + threadIdx.x;
    if (e >= NE) return;
    int d   = dst[e];
    int pos = atomicAdd(&cnt[d], 1);
    if (pos < STRIDE) {           // safety clamp (prob ~0 on this dataset)
        int q = d * STRIDE + pos;
        esrc[q] = src[e];
        ew[q]   = w[e];
    }
}

// Within-chunk degree sort: one wave per 64-node chunk, register bitonic via
// shfl_xor. perm[chunk*64+rank] = chunk*64 + local_of_rank (degree-ascending).
// Keeps all reads/writes inside the chunk window (locality preserved) while
// giving each 16-node wave-quad near-uniform trip counts.
__global__ __launch_bounds__(64) void k_sort(const int* __restrict__ cnt,
                                             int* __restrict__ perm) {
    int chunk = blockIdx.x;
    int lane  = threadIdx.x;
    int n   = chunk * 64 + lane;
    int deg = (n < NN) ? cnt[n] : 0x7FFF;   // invalid nodes sort to the end
    int val = (deg << 6) | lane;            // unique keys -> deterministic
    #pragma unroll
    for (int k = 2; k <= 64; k <<= 1) {
        #pragma unroll
        for (int j = k >> 1; j > 0; j >>= 1) {
            int other = __shfl_xor(val, j, 64);
            bool keepmin = (((lane & j) == 0) == ((lane & k) == 0));
            val = keepmin ? min(val, other) : max(val, other);
        }
    }
    perm[chunk * 64 + lane] = chunk * 64 + (val & 63);
}

// ================= CSR fallback build =================

__global__ void k_hist(const int* __restrict__ dst, int* __restrict__ counts) {
    int e = blockIdx.x * blockDim.x + threadIdx.x;
    if (e < NE) atomicAdd(&counts[dst[e]], 1);
}

__global__ __launch_bounds__(SCAN_THREADS) void k_scan(const int* __restrict__ counts,
                                                       int* __restrict__ offsets,
                                                       int* __restrict__ cursor,
                                                       int pad) {
    __shared__ int part[SCAN_THREADS];
    int tid = threadIdx.x;
    int begin = tid * SCHUNK;
    int end   = min(begin + SCHUNK, NN);
    int pm = pad - 1;
    int s = 0;
    for (int i = begin; i < end; ++i) s += (counts[i] + pm) & ~pm;
    part[tid] = s;
    __syncthreads();
    for (int off = 1; off < SCAN_THREADS; off <<= 1) {
        int v = (tid >= off) ? part[tid - off] : 0;
        __syncthreads();
        part[tid] += v;
        __syncthreads();
    }
    int run = (tid == 0) ? 0 : part[tid - 1];
    for (int i = begin; i < end; ++i) {
        offsets[i] = run;
        cursor[i]  = run;
        run += (counts[i] + pm) & ~pm;
    }
    if (tid == SCAN_THREADS - 1) offsets[NN] = part[SCAN_THREADS - 1];
}

__global__ void k_scatter_pad(const int* __restrict__ src, const int* __restrict__ dst,
                              const float* __restrict__ w,
                              const int* __restrict__ counts,
                              const int* __restrict__ offsets,
                              int* __restrict__ cursor,
                              int* __restrict__ esrc, float* __restrict__ ew) {
    int b = blockIdx.x;
    if (b < SCAT_BLK) {
        int e = b * blockDim.x + threadIdx.x;
        if (e >= NE) return;
        int d = dst[e];
        int pos = atomicAdd(&cursor[d], 1);
        esrc[pos] = src[e];
        ew[pos]   = w[e];
    } else {
        int n = (b - SCAT_BLK) * blockDim.x + threadIdx.x;
        if (n >= NN) return;
        int d    = counts[n];
        int beg  = offsets[n];
        int pdeg = (d + 3) & ~3;
        const float qnan = __int_as_float(0x7FC00000);
        for (int p = beg + d; p < beg + pdeg; ++p) { esrc[p] = 0; ew[p] = qnan; }
    }
}

// ================= main gather-max =================
// One block = (bt pair {bt0, bt0+48}, 64-node chunk). 256 thr = 64 nodes x 4 d4.
// XCD pinning: idx%8 = XCD -> 1.28 MB V pair stays L2-resident.
// 2-deep software pipeline; edge loads for stage t+2 issued BEFORE gathers of
// stage t+1 so consuming stage t waits only its own 8 gathers (in-order vmcnt).
// MODE 0: fixed-stride rows + within-chunk degree-sorted perm.
// MODE 1: CSR padded. MODE 2: CSR unpadded scalar loop.

struct Regs {
    float4 a0, a1, a2, a3, b0, b1, b2, b3;
};

__device__ __forceinline__ void gather(Regs& g, const float* __restrict__ Va,
                                       const float* __restrict__ Vb, int4 ss) {
    g.a0 = *reinterpret_cast<const float4*>(Va + ss.x * DD);
    g.a1 = *reinterpret_cast<const float4*>(Va + ss.y * DD);
    g.a2 = *reinterpret_cast<const float4*>(Va + ss.z * DD);
    g.a3 = *reinterpret_cast<const float4*>(Va + ss.w * DD);
    g.b0 = *reinterpret_cast<const float4*>(Vb + ss.x * DD);
    g.b1 = *reinterpret_cast<const float4*>(Vb + ss.y * DD);
    g.b2 = *reinterpret_cast<const float4*>(Vb + ss.z * DD);
    g.b3 = *reinterpret_cast<const float4*>(Vb + ss.w * DD);
}

__device__ __forceinline__ void consume(const Regs& g, float4 wv,
                                        float4& accA, float4& accB) {
    accA.x = fmaxf(accA.x, fmaxf(fmaxf(g.a0.x*wv.x, g.a1.x*wv.y), fmaxf(g.a2.x*wv.z, g.a3.x*wv.w)));
    accA.y = fmaxf(accA.y, fmaxf(fmaxf(g.a0.y*wv.x, g.a1.y*wv.y), fmaxf(g.a2.y*wv.z, g.a3.y*wv.w)));
    accA.z = fmaxf(accA.z, fmaxf(fmaxf(g.a0.z*wv.x, g.a1.z*wv.y), fmaxf(g.a2.z*wv.z, g.a3.z*wv.w)));
    accA.w = fmaxf(accA.w, fmaxf(fmaxf(g.a0.w*wv.x, g.a1.w*wv.y), fmaxf(g.a2.w*wv.z, g.a3.w*wv.w)));
    accB.x = fmaxf(accB.x, fmaxf(fmaxf(g.b0.x*wv.x, g.b1.x*wv.y), fmaxf(g.b2.x*wv.z, g.b3.x*wv.w)));
    accB.y = fmaxf(accB.y, fmaxf(fmaxf(g.b0.y*wv.x, g.b1.y*wv.y), fmaxf(g.b2.y*wv.z, g.b3.y*wv.w)));
    accB.z = fmaxf(accB.z, fmaxf(fmaxf(g.b0.z*wv.x, g.b1.z*wv.y), fmaxf(g.b2.z*wv.z, g.b3.z*wv.w)));
    accB.w = fmaxf(accB.w, fmaxf(fmaxf(g.b0.w*wv.x, g.b1.w*wv.y), fmaxf(g.b2.w*wv.z, g.b3.w*wv.w)));
}

template <int MODE>
__global__ __launch_bounds__(256) void k_main(const float* __restrict__ V,
                                              const int* __restrict__ meta,
                                              const int* __restrict__ perm,
                                              const int* __restrict__ esrc,
                                              const float* __restrict__ ew,
                                              float* __restrict__ out) {
    int idx = blockIdx.x;
    int r   = idx & 7;
    int k   = idx >> 3;
    int btd = k / NCHUNK;             // 0..5
    int chunk = k - btd * NCHUNK;     // 0..156
    int bt0 = r + 8 * btd;            // 0..47
    int bt1 = bt0 + 48;               // 48..95

    int tid = threadIdx.x;
    int i0  = chunk * NODES_PER_BLOCK + (tid >> 2);
    int d4  = (tid & 3) << 2;
    int n   = (MODE == 0) ? perm[i0] : i0;
    if (n >= NN) return;              // no LDS/sync: early-exit safe

    const float* __restrict__ Va = V + (size_t)bt0 * (NN * DD) + d4;
    const float* __restrict__ Vb = V + (size_t)bt1 * (NN * DD) + d4;

    const float ninf = -__builtin_huge_valf();
    float4 accA = {ninf, ninf, ninf, ninf};
    float4 accB = {ninf, ninf, ninf, ninf};

    if (MODE == 0 || MODE == 1) {
        int beg, trips;
        if (MODE == 0) {
            beg   = n * STRIDE;
            trips = (meta[n] + 3) >> 2;   // pad slots NaN-filled by k_init
        } else {
            beg   = meta[n];
            trips = (meta[n + 1] - beg) >> 2;
        }
        if (trips > 0) {
            const int4*   ep = reinterpret_cast<const int4*>(esrc + beg);
            const float4* wp = reinterpret_cast<const float4*>(ew + beg);

            Regs g0, g1;

            int4 ss0 = ep[0]; float4 ww0 = wp[0];
            int4 ss1 = ss0;   float4 ww1 = ww0;
            if (trips > 1) { ss1 = ep[1]; ww1 = wp[1]; }
            gather(g0, Va, Vb, ss0);

            int t = 0;
            for (; t + 2 < trips; t += 2) {
                float4 wc0 = ww0;
                ss0 = ep[t+2]; ww0 = wp[t+2];        // edge t+2 in flight first
                gather(g1, Va, Vb, ss1);             // gathers t+1
                consume(g0, wc0, accA, accB);        // waits gathers t only
                float4 wc1 = ww1;
                if (t + 3 < trips) { ss1 = ep[t+3]; ww1 = wp[t+3]; }
                gather(g0, Va, Vb, ss0);             // gathers t+2
                consume(g1, wc1, accA, accB);        // waits gathers t+1 only
            }
            if (t + 1 < trips) {
                gather(g1, Va, Vb, ss1);
                consume(g0, ww0, accA, accB);
                consume(g1, ww1, accA, accB);
            } else {
                consume(g0, ww0, accA, accB);
            }
        }
    } else {
        int beg = meta[n], endo = meta[n + 1];
        for (int j = beg; j < endo; ++j) {
            int   s  = esrc[j];
            float we = ew[j];
            float4 a = *reinterpret_cast<const float4*>(Va + s * DD);
            float4 b = *reinterpret_cast<const float4*>(Vb + s * DD);
            accA.x = fmaxf(accA.x, a.x * we);
            accA.y = fmaxf(accA.y, a.y * we);
            accA.z = fmaxf(accA.z, a.z * we);
            accA.w = fmaxf(accA.w, a.w * we);
            accB.x = fmaxf(accB.x, b.x * we);
            accB.y = fmaxf(accB.y, b.y * we);
            accB.z = fmaxf(accB.z, b.z * we);
            accB.w = fmaxf(accB.w, b.w * we);
        }
    }

    float4 ra, rb;
    ra.x = (accA.x == ninf) ? 0.0f : accA.x;
    ra.y = (accA.y == ninf) ? 0.0f : accA.y;
    ra.z = (accA.z == ninf) ? 0.0f : accA.z;
    ra.w = (accA.w == ninf) ? 0.0f : accA.w;
    rb.x = (accB.x == ninf) ? 0.0f : accB.x;
    rb.y = (accB.y == ninf) ? 0.0f : accB.y;
    rb.z = (accB.z == ninf) ? 0.0f : accB.z;
    rb.w = (accB.w == ninf) ? 0.0f : accB.w;
    *reinterpret_cast<float4*>(out + ((size_t)bt0 * NN + n) * DD + d4) = ra;
    *reinterpret_cast<float4*>(out + ((size_t)bt1 * NN + n) * DD + d4) = rb;
}

// ================= launch =================

extern "C" void kernel_launch(void* const* d_in, const int* in_sizes, int n_in,
                              void* d_out, int out_size, void* d_ws, size_t ws_size,
                              hipStream_t stream) {
    const float* V   = (const float*)d_in[0];
    const int*   src = (const int*)d_in[1];
    const int*   dst = (const int*)d_in[2];
    const float* w   = (const float*)d_in[3];
    float* out = (float*)d_out;

    int nblocks = NXCD * BTD_MAX * NCHUNK;   // 7536
    int* ws_i = (int*)d_ws;

    // direct path ws layout (4B elems, 16B-aligned):
    // esrc[NROW] | ew[NROW] | cnt[NN] | perm[NPERM]
    size_t need_direct = (size_t)(2 * NROW + NN + NPERM) * 4;

    if (ws_size >= need_direct) {
        int*   esrc = ws_i;
        float* ew   = (float*)(ws_i + NROW);
        int*   cnt  = ws_i + 2 * NROW;
        int*   perm = ws_i + 2 * NROW + NN;

        k_init<<<1280, 256, 0, stream>>>(esrc, ew, cnt);
        k_scat<<<(NE + 255) / 256, 256, 0, stream>>>(src, dst, w, cnt, esrc, ew);
        k_sort<<<NCHUNK, 64, 0, stream>>>(cnt, perm);
        k_main<0><<<nblocks, 256, 0, stream>>>(V, cnt, perm, esrc, ew, out);
        return;
    }

    // CSR fallback: esrc[NEP] | ew[NEP] | counts[NN] | offsets[NN+1] | cursor[NN]
    size_t need_csr = (size_t)(2 * NEP + 3 * NN + 1) * 4;
    int*   esrc    = ws_i;
    float* ew      = (float*)(ws_i + NEP);
    int*   counts  = ws_i + 2 * NEP;
    int*   offsets = counts + NN;
    int*   cursor  = offsets + NN + 1;

    bool padded = ws_size >= need_csr;

    (void)hipMemsetAsync(counts, 0, NN * sizeof(int), stream);
    k_hist<<<(NE + 255) / 256, 256, 0, stream>>>(dst, counts);
    k_scan<<<1, SCAN_THREADS, 0, stream>>>(counts, offsets, cursor, padded ? 4 : 1);
    if (padded) {
        int pad_blk = (NN + 255) / 256;
        k_scatter_pad<<<SCAT_BLK + pad_blk, 256, 0, stream>>>(src, dst, w, counts,
                                                              offsets, cursor, esrc, ew);
        k_main<1><<<nblocks, 256, 0, stream>>>(V, offsets, nullptr, esrc, ew, out);
    } else {
        k_scatter_pad<<<SCAT_BLK, 256, 0, stream>>>(src, dst, w, counts,
                                                    offsets, cursor, esrc, ew);
        k_main<2><<<nblocks, 256, 0, stream>>>(V, offsets, nullptr, esrc, ew, out);
    }
}